// Round 1
// baseline (5199.568 us; speedup 1.0000x reference)
//
#include <hip/hip_runtime.h>
#include <cstdint>
#include <cstddef>

#define N_NODES 100000
#define DIM 512
#define NE 200000

// ---------------- Wc = (W0+W1+W2)/3 ----------------
__global__ __launch_bounds__(256) void combine_w_kernel(
    const float* __restrict__ W0, const float* __restrict__ W1,
    const float* __restrict__ W2, float* __restrict__ Wc) {
    int i = blockIdx.x * 256 + threadIdx.x;   // exactly 512*512 threads launched
    Wc[i] = (W0[i] + W1[i] + W2[i]) * (1.0f / 3.0f);
}

// ---------------- per-etype in-degree counts ----------------
__global__ __launch_bounds__(256) void count_kernel(
    const int* __restrict__ d0, const int* __restrict__ d1,
    const int* __restrict__ d2, int* __restrict__ cnt) {
    int t = blockIdx.x * 256 + threadIdx.x;
    if (t >= 3 * NE) return;
    int e = t / NE;
    int i = t - e * NE;
    const int* dp = (e == 0) ? d0 : (e == 1) ? d1 : d2;
    atomicAdd(&cnt[e * N_NODES + dp[i]], 1);
}

// ---------------- inv[e][n] = 1/(3*max(cnt,1)) ----------------
__global__ __launch_bounds__(256) void inv_kernel(
    const int* __restrict__ cnt, float* __restrict__ inv) {
    int t = blockIdx.x * 256 + threadIdx.x;
    if (t >= 3 * N_NODES) return;
    int c = cnt[t];
    if (c < 1) c = 1;
    inv[t] = 1.0f / (3.0f * (float)c);
}

// ---------------- scatter: xagg[dst] += x[src] * inv[e][dst] ----------------
// one wave (64 lanes) per edge; each lane handles 8 floats (2 x float4)
__global__ __launch_bounds__(256) void scatter_kernel(
    const float* __restrict__ x,
    const int* __restrict__ s0, const int* __restrict__ d0,
    const int* __restrict__ s1, const int* __restrict__ d1,
    const int* __restrict__ s2, const int* __restrict__ d2,
    const float* __restrict__ inv, float* __restrict__ xagg) {
    int lane = threadIdx.x & 63;
    int wv = threadIdx.x >> 6;
    int eg = blockIdx.x * 4 + wv;         // 0 .. 3*NE-1  (grid sized exactly)
    if (eg >= 3 * NE) return;
    int e = eg / NE;
    int i = eg - e * NE;
    const int* sp; const int* dp;
    if (e == 0)      { sp = s0; dp = d0; }
    else if (e == 1) { sp = s1; dp = d1; }
    else             { sp = s2; dp = d2; }
    int s = sp[i];
    int d = dp[i];
    float w = inv[e * N_NODES + d];
    const float4* xp = (const float4*)(x + (size_t)s * DIM);
    float*        op = xagg + (size_t)d * DIM;
    float4 v0 = xp[lane];
    float4 v1 = xp[lane + 64];
    int b0 = lane * 4;
    int b1 = 256 + lane * 4;
    unsafeAtomicAdd(op + b0 + 0, v0.x * w);
    unsafeAtomicAdd(op + b0 + 1, v0.y * w);
    unsafeAtomicAdd(op + b0 + 2, v0.z * w);
    unsafeAtomicAdd(op + b0 + 3, v0.w * w);
    unsafeAtomicAdd(op + b1 + 0, v1.x * w);
    unsafeAtomicAdd(op + b1 + 1, v1.y * w);
    unsafeAtomicAdd(op + b1 + 2, v1.z * w);
    unsafeAtomicAdd(op + b1 + 3, v1.w * w);
}

// ---------------- fp32 GEMM: C[m,n] = sum_k A[m,k] * B[n,k] ----------------
// A = xagg [M, 512] row-major, B = Wc [512, 512] row-major (B^T layout)
#define BM 64
#define BN 64
#define BK 32
__global__ __launch_bounds__(256) void sgemm_bt_kernel(
    const float* __restrict__ A, const float* __restrict__ B,
    float* __restrict__ C, int M) {
    __shared__ float As[BK][BM];
    __shared__ float Bs[BK][BN];
    const int tid = threadIdx.x;
    const int tx = tid & 15;
    const int ty = tid >> 4;
    const int m0 = blockIdx.y * BM;
    const int n0 = blockIdx.x * BN;
    float acc[4][4] = {};
    for (int k0 = 0; k0 < DIM; k0 += BK) {
        // load A tile (64 rows x 32 k): 512 float4s over 256 threads
        #pragma unroll
        for (int l = 0; l < 2; ++l) {
            int idx = tid + l * 256;
            int row = idx >> 3;      // 0..63
            int c4  = idx & 7;       // 0..7
            int gm = m0 + row;
            float4 v = make_float4(0.f, 0.f, 0.f, 0.f);
            if (gm < M) v = *(const float4*)&A[(size_t)gm * DIM + k0 + c4 * 4];
            As[c4 * 4 + 0][row] = v.x;
            As[c4 * 4 + 1][row] = v.y;
            As[c4 * 4 + 2][row] = v.z;
            As[c4 * 4 + 3][row] = v.w;
        }
        #pragma unroll
        for (int l = 0; l < 2; ++l) {
            int idx = tid + l * 256;
            int row = idx >> 3;
            int c4  = idx & 7;
            int gn = n0 + row;       // always < 512
            float4 v = *(const float4*)&B[(size_t)gn * DIM + k0 + c4 * 4];
            Bs[c4 * 4 + 0][row] = v.x;
            Bs[c4 * 4 + 1][row] = v.y;
            Bs[c4 * 4 + 2][row] = v.z;
            Bs[c4 * 4 + 3][row] = v.w;
        }
        __syncthreads();
        #pragma unroll
        for (int kk = 0; kk < BK; ++kk) {
            float4 ra = *(const float4*)&As[kk][ty * 4];
            float4 rb = *(const float4*)&Bs[kk][tx * 4];
            float a[4] = {ra.x, ra.y, ra.z, ra.w};
            float b[4] = {rb.x, rb.y, rb.z, rb.w};
            #pragma unroll
            for (int i = 0; i < 4; ++i)
                #pragma unroll
                for (int j = 0; j < 4; ++j)
                    acc[i][j] += a[i] * b[j];
        }
        __syncthreads();
    }
    #pragma unroll
    for (int i = 0; i < 4; ++i) {
        int gm = m0 + ty * 4 + i;
        if (gm < M) {
            float4 v = make_float4(acc[i][0], acc[i][1], acc[i][2], acc[i][3]);
            *(float4*)&C[(size_t)gm * DIM + n0 + tx * 4] = v;
        }
    }
}

// ---------------- fused ReLU + LayerNorm, in-place, one wave per row ----------------
__global__ __launch_bounds__(256) void relu_ln_kernel(
    float* __restrict__ io, const float* __restrict__ gamma,
    const float* __restrict__ beta, int n_rows) {
    int lane = threadIdx.x & 63;
    int wv = threadIdx.x >> 6;
    int row = blockIdx.x * 4 + wv;
    if (row >= n_rows) return;
    float* p = io + (size_t)row * DIM;
    float4 a0 = ((const float4*)p)[lane];
    float4 a1 = ((const float4*)p)[lane + 64];
    a0.x = fmaxf(a0.x, 0.f); a0.y = fmaxf(a0.y, 0.f);
    a0.z = fmaxf(a0.z, 0.f); a0.w = fmaxf(a0.w, 0.f);
    a1.x = fmaxf(a1.x, 0.f); a1.y = fmaxf(a1.y, 0.f);
    a1.z = fmaxf(a1.z, 0.f); a1.w = fmaxf(a1.w, 0.f);
    float s  = a0.x + a0.y + a0.z + a0.w + a1.x + a1.y + a1.z + a1.w;
    float sq = a0.x*a0.x + a0.y*a0.y + a0.z*a0.z + a0.w*a0.w
             + a1.x*a1.x + a1.y*a1.y + a1.z*a1.z + a1.w*a1.w;
    #pragma unroll
    for (int off = 32; off > 0; off >>= 1) {
        s  += __shfl_xor(s, off);
        sq += __shfl_xor(sq, off);
    }
    float mu  = s * (1.0f / DIM);
    float var = sq * (1.0f / DIM) - mu * mu;
    float rstd = rsqrtf(var + 1e-5f);
    float4 g0 = ((const float4*)gamma)[lane];
    float4 g1 = ((const float4*)gamma)[lane + 64];
    float4 b0 = ((const float4*)beta)[lane];
    float4 b1 = ((const float4*)beta)[lane + 64];
    float4 o0, o1;
    o0.x = (a0.x - mu) * rstd * g0.x + b0.x;
    o0.y = (a0.y - mu) * rstd * g0.y + b0.y;
    o0.z = (a0.z - mu) * rstd * g0.z + b0.z;
    o0.w = (a0.w - mu) * rstd * g0.w + b0.w;
    o1.x = (a1.x - mu) * rstd * g1.x + b1.x;
    o1.y = (a1.y - mu) * rstd * g1.y + b1.y;
    o1.z = (a1.z - mu) * rstd * g1.z + b1.z;
    o1.w = (a1.w - mu) * rstd * g1.w + b1.w;
    ((float4*)p)[lane] = o0;
    ((float4*)p)[lane + 64] = o1;
}

extern "C" void kernel_launch(void* const* d_in, const int* in_sizes, int n_in,
                              void* d_out, int out_size, void* d_ws, size_t ws_size,
                              hipStream_t stream) {
    const float* x     = (const float*)d_in[0];
    const float* W0    = (const float*)d_in[1];
    const float* W1    = (const float*)d_in[2];
    const float* W2    = (const float*)d_in[3];
    const float* gamma = (const float*)d_in[4];
    const float* beta  = (const float*)d_in[5];
    const int* s0 = (const int*)d_in[6];
    const int* dd0 = (const int*)d_in[7];
    const int* s1 = (const int*)d_in[8];
    const int* dd1 = (const int*)d_in[9];
    const int* s2 = (const int*)d_in[10];
    const int* dd2 = (const int*)d_in[11];
    float* out = (float*)d_out;

    // workspace layout
    char* ws = (char*)d_ws;
    float* Wc   = (float*)ws;                                         // 1 MiB
    float* xagg = (float*)(ws + (1u << 20));                          // 204.8 MB
    int*   cnt  = (int*)  (ws + (1u << 20) + 204800000u);             // 1.2 MB
    float* inv  = (float*)(ws + (1u << 20) + 204800000u + 1200000u);  // 1.2 MB

    hipMemsetAsync(xagg, 0, (size_t)N_NODES * DIM * sizeof(float), stream);
    hipMemsetAsync(cnt, 0, (size_t)3 * N_NODES * sizeof(int), stream);

    combine_w_kernel<<<(DIM * DIM) / 256, 256, 0, stream>>>(W0, W1, W2, Wc);
    count_kernel<<<(3 * NE + 255) / 256, 256, 0, stream>>>(dd0, dd1, dd2, cnt);
    inv_kernel<<<(3 * N_NODES + 255) / 256, 256, 0, stream>>>(cnt, inv);
    scatter_kernel<<<(3 * NE) / 4, 256, 0, stream>>>(x, s0, dd0, s1, dd1, s2, dd2, inv, xagg);

    dim3 gemm_grid(DIM / BN, (N_NODES + BM - 1) / BM);
    sgemm_bt_kernel<<<gemm_grid, 256, 0, stream>>>(xagg, Wc, out, N_NODES);

    relu_ln_kernel<<<(N_NODES + 3) / 4, 256, 0, stream>>>(out, gamma, beta, N_NODES);
}

// Round 2
// 766.932 us; speedup vs baseline: 6.7797x; 6.7797x over previous
//
#include <hip/hip_runtime.h>
#include <cstdint>
#include <cstddef>

#define N_NODES 100000
#define DIM 512
#define NE 200000
#define NBLK 391   // ceil(N_NODES/256)

typedef __attribute__((ext_vector_type(4))) float floatx4;
typedef __attribute__((ext_vector_type(8))) short shortx8;

__device__ __forceinline__ unsigned short f2bf(float f) {
    union { float f; uint32_t u; } v; v.f = f;
    uint32_t r = v.u + 0x7fff + ((v.u >> 16) & 1);   // RNE
    return (unsigned short)(r >> 16);
}

__device__ __forceinline__ void load_lds16(const void* g, void* l) {
    __builtin_amdgcn_global_load_lds(
        (const __attribute__((address_space(1))) uint32_t*)g,
        (__attribute__((address_space(3))) uint32_t*)l, 16, 0, 0);
}

// ---------------- Wc = (W0+W1+W2)/3 -> bf16 ----------------
__global__ __launch_bounds__(256) void combine_w_kernel(
    const float* __restrict__ W0, const float* __restrict__ W1,
    const float* __restrict__ W2, unsigned short* __restrict__ Wc) {
    int i = blockIdx.x * 256 + threadIdx.x;   // exactly 512*512 threads
    Wc[i] = f2bf((W0[i] + W1[i] + W2[i]) * (1.0f / 3.0f));
}

// ---------------- per-etype in-degree counts ----------------
__global__ __launch_bounds__(256) void count_kernel(
    const int* __restrict__ d0, const int* __restrict__ d1,
    const int* __restrict__ d2, int* __restrict__ cnt) {
    int t = blockIdx.x * 256 + threadIdx.x;
    if (t >= 3 * NE) return;
    int e = t / NE;
    int i = t - e * NE;
    const int* dp = (e == 0) ? d0 : (e == 1) ? d1 : d2;
    atomicAdd(&cnt[e * N_NODES + dp[i]], 1);
}

// ---------------- scan pass 1: per-block sums of total row length ----------------
__global__ __launch_bounds__(256) void scan1_kernel(
    const int* __restrict__ cnt, int* __restrict__ bsum) {
    int t = threadIdx.x;
    int n = blockIdx.x * 256 + t;
    int rl = 0;
    if (n < N_NODES) rl = cnt[n] + cnt[N_NODES + n] + cnt[2 * N_NODES + n];
    int v = rl;
    #pragma unroll
    for (int off = 32; off > 0; off >>= 1) v += __shfl_xor(v, off);
    __shared__ int ws_[4];
    if ((t & 63) == 0) ws_[t >> 6] = v;
    __syncthreads();
    if (t == 0) bsum[blockIdx.x] = ws_[0] + ws_[1] + ws_[2] + ws_[3];
}

// ---------------- scan pass 2: exclusive scan of block sums (1 block) ----------------
__global__ __launch_bounds__(512) void scan2_kernel(
    const int* __restrict__ bsum, int* __restrict__ boff) {
    __shared__ int sh[512];
    int t = threadIdx.x;
    int v = (t < NBLK) ? bsum[t] : 0;
    sh[t] = v;
    __syncthreads();
    #pragma unroll
    for (int off = 1; off < 512; off <<= 1) {
        int add = (t >= off) ? sh[t - off] : 0;
        __syncthreads();
        sh[t] += add;
        __syncthreads();
    }
    if (t < NBLK) boff[t] = sh[t] - v;   // exclusive
}

// ---------------- scan pass 3: row_start + cursor ----------------
__global__ __launch_bounds__(256) void scan3_kernel(
    const int* __restrict__ cnt, const int* __restrict__ boff,
    int* __restrict__ row_start, int* __restrict__ cursor) {
    __shared__ int sh[256];
    int t = threadIdx.x;
    int n = blockIdx.x * 256 + t;
    int rl = 0;
    if (n < N_NODES) rl = cnt[n] + cnt[N_NODES + n] + cnt[2 * N_NODES + n];
    sh[t] = rl;
    __syncthreads();
    #pragma unroll
    for (int off = 1; off < 256; off <<= 1) {
        int add = (t >= off) ? sh[t - off] : 0;
        __syncthreads();
        sh[t] += add;
        __syncthreads();
    }
    if (n < N_NODES) {
        int excl = sh[t] - rl + boff[blockIdx.x];
        row_start[n] = excl;
        cursor[n] = excl;
    }
}

// ---------------- bin edges into CSR with per-edge weight ----------------
__global__ __launch_bounds__(256) void bin_kernel(
    const int* __restrict__ s0, const int* __restrict__ d0,
    const int* __restrict__ s1, const int* __restrict__ d1,
    const int* __restrict__ s2, const int* __restrict__ d2,
    const int* __restrict__ cnt, int* __restrict__ cursor,
    int* __restrict__ src_all, float* __restrict__ w_all) {
    int t = blockIdx.x * 256 + threadIdx.x;
    if (t >= 3 * NE) return;
    int e = t / NE;
    int i = t - e * NE;
    const int* sp; const int* dp;
    if (e == 0)      { sp = s0; dp = d0; }
    else if (e == 1) { sp = s1; dp = d1; }
    else             { sp = s2; dp = d2; }
    int d = dp[i];
    int c = cnt[e * N_NODES + d];
    if (c < 1) c = 1;
    float w = 1.0f / (3.0f * (float)c);
    int pos = atomicAdd(&cursor[d], 1);
    src_all[pos] = sp[i];
    w_all[pos] = w;
}

// ---------------- gather: xagg[n] = sum_j w_j * x[src_j], one wave per node ----------------
__global__ __launch_bounds__(256) void gather_kernel(
    const float* __restrict__ x, const int* __restrict__ row_start,
    const int* __restrict__ cnt, const int* __restrict__ src_all,
    const float* __restrict__ w_all, unsigned short* __restrict__ xagg) {
    int lane = threadIdx.x & 63;
    int n = blockIdx.x * 4 + (threadIdx.x >> 6);
    if (n >= N_NODES) return;
    int beg = row_start[n];
    int len = cnt[n] + cnt[N_NODES + n] + cnt[2 * N_NODES + n];
    float4 a0 = make_float4(0.f, 0.f, 0.f, 0.f);
    float4 a1 = make_float4(0.f, 0.f, 0.f, 0.f);
    for (int j = beg; j < beg + len; ++j) {
        int s = src_all[j];
        float w = w_all[j];
        const float4* xp = (const float4*)(x + (size_t)s * DIM);
        float4 v0 = xp[lane];
        float4 v1 = xp[lane + 64];
        a0.x += v0.x * w; a0.y += v0.y * w; a0.z += v0.z * w; a0.w += v0.w * w;
        a1.x += v1.x * w; a1.y += v1.y * w; a1.z += v1.z * w; a1.w += v1.w * w;
    }
    ushort4 o0, o1;
    o0.x = f2bf(a0.x); o0.y = f2bf(a0.y); o0.z = f2bf(a0.z); o0.w = f2bf(a0.w);
    o1.x = f2bf(a1.x); o1.y = f2bf(a1.y); o1.z = f2bf(a1.z); o1.w = f2bf(a1.w);
    unsigned short* op = xagg + (size_t)n * DIM;
    ((ushort4*)op)[lane] = o0;
    ((ushort4*)(op + 256))[lane] = o1;
}

// ---------------- bf16 MFMA GEMM: C[m,n] = sum_k A[m,k]*B[n,k] ----------------
// A = xagg [M,512] bf16, B = Wc [512,512] bf16 (B^T layout), C fp32
__global__ __launch_bounds__(256) void gemm_bf16_kernel(
    const unsigned short* __restrict__ A, const unsigned short* __restrict__ B,
    float* __restrict__ C, int M) {
    // LDS layout: [k-octet 0..3][row 0..127][8 bf16] = 8 KB each
    __shared__ unsigned short As[4 * 128 * 8];
    __shared__ unsigned short Bs[4 * 128 * 8];
    const int tid = threadIdx.x;
    const int lane = tid & 63;
    const int wv = tid >> 6;
    const int m0 = blockIdx.y * 128;
    const int n0 = blockIdx.x * 128;
    const int wm = (wv >> 1) * 64;
    const int wn = (wv & 1) * 64;
    const int q = lane >> 4;       // k-octet / D-row-quad
    const int r = lane & 15;

    floatx4 acc[4][4] = {};

    for (int k0 = 0; k0 < DIM; k0 += 32) {
        #pragma unroll
        for (int it = 0; it < 2; ++it) {
            int idx = it * 256 + tid;
            int c = idx >> 7;          // 0..3 k-octet
            int row = idx & 127;       // 0..127
            int gm = m0 + row; if (gm >= M) gm = M - 1;
            load_lds16(&A[(size_t)gm * DIM + k0 + c * 8], &As[(c * 128 + row) * 8]);
            load_lds16(&B[(size_t)(n0 + row) * DIM + k0 + c * 8], &Bs[(c * 128 + row) * 8]);
        }
        __syncthreads();
        shortx8 af[4], bf[4];
        #pragma unroll
        for (int mi = 0; mi < 4; ++mi)
            af[mi] = *(const shortx8*)&As[(q * 128 + wm + mi * 16 + r) * 8];
        #pragma unroll
        for (int nj = 0; nj < 4; ++nj)
            bf[nj] = *(const shortx8*)&Bs[(q * 128 + wn + nj * 16 + r) * 8];
        #pragma unroll
        for (int mi = 0; mi < 4; ++mi)
            #pragma unroll
            for (int nj = 0; nj < 4; ++nj)
                acc[mi][nj] = __builtin_amdgcn_mfma_f32_16x16x32_bf16(
                    af[mi], bf[nj], acc[mi][nj], 0, 0, 0);
        __syncthreads();
    }
    // C/D layout: row = q*4 + reg, col = r  (per 16x16 tile)
    #pragma unroll
    for (int mi = 0; mi < 4; ++mi) {
        #pragma unroll
        for (int rg = 0; rg < 4; ++rg) {
            int gm = m0 + wm + mi * 16 + q * 4 + rg;
            if (gm < M) {
                #pragma unroll
                for (int nj = 0; nj < 4; ++nj) {
                    int gn = n0 + wn + nj * 16 + r;
                    C[(size_t)gm * DIM + gn] = acc[mi][nj][rg];
                }
            }
        }
    }
}

// ---------------- fused ReLU + LayerNorm, in-place, one wave per row ----------------
__global__ __launch_bounds__(256) void relu_ln_kernel(
    float* __restrict__ io, const float* __restrict__ gamma,
    const float* __restrict__ beta, int n_rows) {
    int lane = threadIdx.x & 63;
    int wv = threadIdx.x >> 6;
    int row = blockIdx.x * 4 + wv;
    if (row >= n_rows) return;
    float* p = io + (size_t)row * DIM;
    float4 a0 = ((const float4*)p)[lane];
    float4 a1 = ((const float4*)p)[lane + 64];
    a0.x = fmaxf(a0.x, 0.f); a0.y = fmaxf(a0.y, 0.f);
    a0.z = fmaxf(a0.z, 0.f); a0.w = fmaxf(a0.w, 0.f);
    a1.x = fmaxf(a1.x, 0.f); a1.y = fmaxf(a1.y, 0.f);
    a1.z = fmaxf(a1.z, 0.f); a1.w = fmaxf(a1.w, 0.f);
    float s  = a0.x + a0.y + a0.z + a0.w + a1.x + a1.y + a1.z + a1.w;
    float sq = a0.x*a0.x + a0.y*a0.y + a0.z*a0.z + a0.w*a0.w
             + a1.x*a1.x + a1.y*a1.y + a1.z*a1.z + a1.w*a1.w;
    #pragma unroll
    for (int off = 32; off > 0; off >>= 1) {
        s  += __shfl_xor(s, off);
        sq += __shfl_xor(sq, off);
    }
    float mu  = s * (1.0f / DIM);
    float var = sq * (1.0f / DIM) - mu * mu;
    float rstd = rsqrtf(var + 1e-5f);
    float4 g0 = ((const float4*)gamma)[lane];
    float4 g1 = ((const float4*)gamma)[lane + 64];
    float4 b0 = ((const float4*)beta)[lane];
    float4 b1 = ((const float4*)beta)[lane + 64];
    float4 o0, o1;
    o0.x = (a0.x - mu) * rstd * g0.x + b0.x;
    o0.y = (a0.y - mu) * rstd * g0.y + b0.y;
    o0.z = (a0.z - mu) * rstd * g0.z + b0.z;
    o0.w = (a0.w - mu) * rstd * g0.w + b0.w;
    o1.x = (a1.x - mu) * rstd * g1.x + b1.x;
    o1.y = (a1.y - mu) * rstd * g1.y + b1.y;
    o1.z = (a1.z - mu) * rstd * g1.z + b1.z;
    o1.w = (a1.w - mu) * rstd * g1.w + b1.w;
    ((float4*)p)[lane] = o0;
    ((float4*)p)[lane + 64] = o1;
}

extern "C" void kernel_launch(void* const* d_in, const int* in_sizes, int n_in,
                              void* d_out, int out_size, void* d_ws, size_t ws_size,
                              hipStream_t stream) {
    const float* x     = (const float*)d_in[0];
    const float* W0    = (const float*)d_in[1];
    const float* W1    = (const float*)d_in[2];
    const float* W2    = (const float*)d_in[3];
    const float* gamma = (const float*)d_in[4];
    const float* beta  = (const float*)d_in[5];
    const int* s0  = (const int*)d_in[6];
    const int* dd0 = (const int*)d_in[7];
    const int* s1  = (const int*)d_in[8];
    const int* dd1 = (const int*)d_in[9];
    const int* s2  = (const int*)d_in[10];
    const int* dd2 = (const int*)d_in[11];
    float* out = (float*)d_out;

    // workspace layout (256B aligned)
    char* ws = (char*)d_ws;
    size_t off = 0;
    int* cnt = (int*)(ws + off);             off += 3u * N_NODES * 4u;          // 1.2 MB
    int* row_start = (int*)(ws + off);       off += (size_t)N_NODES * 4u;
    int* cursor = (int*)(ws + off);          off += (size_t)N_NODES * 4u;
    int* bsum = (int*)(ws + off);            off += 2048;
    int* boff = (int*)(ws + off);            off += 2048;
    int* src_all = (int*)(ws + off);         off += (size_t)3 * NE * 4u;        // 2.4 MB
    float* w_all = (float*)(ws + off);       off += (size_t)3 * NE * 4u;        // 2.4 MB
    unsigned short* Wc = (unsigned short*)(ws + off); off += (size_t)DIM * DIM * 2u;
    off = (off + 255) & ~255ull;
    unsigned short* xagg = (unsigned short*)(ws + off);  // 102.4 MB

    hipMemsetAsync(cnt, 0, (size_t)3 * N_NODES * sizeof(int), stream);

    combine_w_kernel<<<(DIM * DIM) / 256, 256, 0, stream>>>(W0, W1, W2, Wc);
    count_kernel<<<(3 * NE + 255) / 256, 256, 0, stream>>>(dd0, dd1, dd2, cnt);
    scan1_kernel<<<NBLK, 256, 0, stream>>>(cnt, bsum);
    scan2_kernel<<<1, 512, 0, stream>>>(bsum, boff);
    scan3_kernel<<<NBLK, 256, 0, stream>>>(cnt, boff, row_start, cursor);
    bin_kernel<<<(3 * NE + 255) / 256, 256, 0, stream>>>(
        s0, dd0, s1, dd1, s2, dd2, cnt, cursor, src_all, w_all);
    gather_kernel<<<(N_NODES + 3) / 4, 256, 0, stream>>>(
        x, row_start, cnt, src_all, w_all, xagg);

    dim3 gemm_grid(DIM / 128, (N_NODES + 127) / 128);
    gemm_bf16_kernel<<<gemm_grid, 256, 0, stream>>>(xagg, Wc, out, N_NODES);

    relu_ln_kernel<<<(N_NODES + 3) / 4, 256, 0, stream>>>(out, gamma, beta, N_NODES);
}

// Round 3
// 735.865 us; speedup vs baseline: 7.0659x; 1.0422x over previous
//
#include <hip/hip_runtime.h>
#include <cstdint>
#include <cstddef>

#define N_NODES 100000
#define DIM 512
#define NE 200000
#define NBLK 391   // ceil(N_NODES/256)

typedef __attribute__((ext_vector_type(4))) float floatx4;
typedef __attribute__((ext_vector_type(8))) short shortx8;

__device__ __forceinline__ unsigned short f2bf(float f) {
    union { float f; uint32_t u; } v; v.f = f;
    uint32_t r = v.u + 0x7fff + ((v.u >> 16) & 1);   // RNE
    return (unsigned short)(r >> 16);
}

__device__ __forceinline__ float bf2f(unsigned short h) {
    union { uint32_t u; float f; } v; v.u = ((uint32_t)h) << 16;
    return v.f;
}

__device__ __forceinline__ void load_lds16(const void* g, void* l) {
    __builtin_amdgcn_global_load_lds(
        (const __attribute__((address_space(1))) uint32_t*)g,
        (__attribute__((address_space(3))) uint32_t*)l, 16, 0, 0);
}

// ---------------- Wc = (W0+W1+W2)/3 -> bf16 ----------------
__global__ __launch_bounds__(256) void combine_w_kernel(
    const float* __restrict__ W0, const float* __restrict__ W1,
    const float* __restrict__ W2, unsigned short* __restrict__ Wc) {
    int i = blockIdx.x * 256 + threadIdx.x;   // exactly 512*512 threads
    Wc[i] = f2bf((W0[i] + W1[i] + W2[i]) * (1.0f / 3.0f));
}

// ---------------- x (fp32) -> xb (bf16), 8 elems/thread ----------------
__global__ __launch_bounds__(256) void convert_x_kernel(
    const float* __restrict__ x, unsigned short* __restrict__ xb) {
    size_t t = (size_t)blockIdx.x * 256 + threadIdx.x;   // 6.4M threads exactly
    const float4* xp = (const float4*)(x + t * 8);
    float4 v0 = xp[0];
    float4 v1 = xp[1];
    ushort4 o0, o1;
    o0.x = f2bf(v0.x); o0.y = f2bf(v0.y); o0.z = f2bf(v0.z); o0.w = f2bf(v0.w);
    o1.x = f2bf(v1.x); o1.y = f2bf(v1.y); o1.z = f2bf(v1.z); o1.w = f2bf(v1.w);
    ushort4* op = (ushort4*)(xb + t * 8);
    op[0] = o0;
    op[1] = o1;
}

// ---------------- per-etype in-degree counts ----------------
__global__ __launch_bounds__(256) void count_kernel(
    const int* __restrict__ d0, const int* __restrict__ d1,
    const int* __restrict__ d2, int* __restrict__ cnt) {
    int t = blockIdx.x * 256 + threadIdx.x;
    if (t >= 3 * NE) return;
    int e = t / NE;
    int i = t - e * NE;
    const int* dp = (e == 0) ? d0 : (e == 1) ? d1 : d2;
    atomicAdd(&cnt[e * N_NODES + dp[i]], 1);
}

// ---------------- scan pass 1: per-block sums of total row length ----------------
__global__ __launch_bounds__(256) void scan1_kernel(
    const int* __restrict__ cnt, int* __restrict__ bsum) {
    int t = threadIdx.x;
    int n = blockIdx.x * 256 + t;
    int rl = 0;
    if (n < N_NODES) rl = cnt[n] + cnt[N_NODES + n] + cnt[2 * N_NODES + n];
    int v = rl;
    #pragma unroll
    for (int off = 32; off > 0; off >>= 1) v += __shfl_xor(v, off);
    __shared__ int ws_[4];
    if ((t & 63) == 0) ws_[t >> 6] = v;
    __syncthreads();
    if (t == 0) bsum[blockIdx.x] = ws_[0] + ws_[1] + ws_[2] + ws_[3];
}

// ---------------- scan pass 2: exclusive scan of block sums (1 block) ----------------
__global__ __launch_bounds__(512) void scan2_kernel(
    const int* __restrict__ bsum, int* __restrict__ boff) {
    __shared__ int sh[512];
    int t = threadIdx.x;
    int v = (t < NBLK) ? bsum[t] : 0;
    sh[t] = v;
    __syncthreads();
    #pragma unroll
    for (int off = 1; off < 512; off <<= 1) {
        int add = (t >= off) ? sh[t - off] : 0;
        __syncthreads();
        sh[t] += add;
        __syncthreads();
    }
    if (t < NBLK) boff[t] = sh[t] - v;   // exclusive
}

// ---------------- scan pass 3: row_start + cursor ----------------
__global__ __launch_bounds__(256) void scan3_kernel(
    const int* __restrict__ cnt, const int* __restrict__ boff,
    int* __restrict__ row_start, int* __restrict__ cursor) {
    __shared__ int sh[256];
    int t = threadIdx.x;
    int n = blockIdx.x * 256 + t;
    int rl = 0;
    if (n < N_NODES) rl = cnt[n] + cnt[N_NODES + n] + cnt[2 * N_NODES + n];
    sh[t] = rl;
    __syncthreads();
    #pragma unroll
    for (int off = 1; off < 256; off <<= 1) {
        int add = (t >= off) ? sh[t - off] : 0;
        __syncthreads();
        sh[t] += add;
        __syncthreads();
    }
    if (n < N_NODES) {
        int excl = sh[t] - rl + boff[blockIdx.x];
        row_start[n] = excl;
        cursor[n] = excl;
    }
}

// ---------------- bin edges into CSR: src tagged with etype in bits 30-31 ----------------
__global__ __launch_bounds__(256) void bin_kernel(
    const int* __restrict__ s0, const int* __restrict__ d0,
    const int* __restrict__ s1, const int* __restrict__ d1,
    const int* __restrict__ s2, const int* __restrict__ d2,
    int* __restrict__ cursor, int* __restrict__ src_tag) {
    int t = blockIdx.x * 256 + threadIdx.x;
    if (t >= 3 * NE) return;
    int e = t / NE;
    int i = t - e * NE;
    const int* sp; const int* dp;
    if (e == 0)      { sp = s0; dp = d0; }
    else if (e == 1) { sp = s1; dp = d1; }
    else             { sp = s2; dp = d2; }
    int d = dp[i];
    int pos = atomicAdd(&cursor[d], 1);
    src_tag[pos] = sp[i] | (e << 30);
}

// ---------------- gather: xagg[n] = sum_j w_e(j) * xb[src_j], one wave per node ----------------
__global__ __launch_bounds__(256) void gather_kernel(
    const unsigned short* __restrict__ xb, const int* __restrict__ row_start,
    const int* __restrict__ cnt, const int* __restrict__ src_tag,
    unsigned short* __restrict__ xagg) {
    int lane = threadIdx.x & 63;
    int n = blockIdx.x * 4 + (threadIdx.x >> 6);
    if (n >= N_NODES) return;
    int c0 = cnt[n], c1 = cnt[N_NODES + n], c2 = cnt[2 * N_NODES + n];
    int len = c0 + c1 + c2;
    float w0 = 1.0f / (3.0f * (float)max(c0, 1));
    float w1 = 1.0f / (3.0f * (float)max(c1, 1));
    float w2 = 1.0f / (3.0f * (float)max(c2, 1));
    int beg = row_start[n];
    float acc[8] = {};
    for (int j = beg; j < beg + len; ++j) {
        int u = src_tag[j];
        int e = ((unsigned)u) >> 30;
        int s = u & 0x3FFFFFFF;
        float w = (e == 0) ? w0 : ((e == 1) ? w1 : w2);
        const ushort4* xp = (const ushort4*)(xb + (size_t)s * DIM + lane * 8);
        ushort4 v0 = xp[0];
        ushort4 v1 = xp[1];
        acc[0] += bf2f(v0.x) * w; acc[1] += bf2f(v0.y) * w;
        acc[2] += bf2f(v0.z) * w; acc[3] += bf2f(v0.w) * w;
        acc[4] += bf2f(v1.x) * w; acc[5] += bf2f(v1.y) * w;
        acc[6] += bf2f(v1.z) * w; acc[7] += bf2f(v1.w) * w;
    }
    ushort4 o0, o1;
    o0.x = f2bf(acc[0]); o0.y = f2bf(acc[1]); o0.z = f2bf(acc[2]); o0.w = f2bf(acc[3]);
    o1.x = f2bf(acc[4]); o1.y = f2bf(acc[5]); o1.z = f2bf(acc[6]); o1.w = f2bf(acc[7]);
    ushort4* op = (ushort4*)(xagg + (size_t)n * DIM + lane * 8);
    op[0] = o0;
    op[1] = o1;
}

// ---------------- fused bf16 MFMA GEMM + ReLU + LayerNorm ----------------
// Block: 64 rows x ALL 512 cols, 512 threads (8 waves; wave w owns cols [w*64, w*64+64)).
// A = xagg [M,512] bf16, B = Wc [512,512] bf16 (B^T), out fp32 normalized.
__global__ __launch_bounds__(512, 4) void gemm_ln_kernel(
    const unsigned short* __restrict__ A, const unsigned short* __restrict__ B,
    const float* __restrict__ gamma, const float* __restrict__ beta,
    float* __restrict__ C, int M) {
    // chunk id 0..255 -> A: [c(0..3)][row(0..63)] ; 256..2303 -> B: [c(0..3)][n(0..511)]
    __shared__ alignas(16) unsigned short Asb[64 * 32];    //  4 KB
    __shared__ alignas(16) unsigned short Bsb[512 * 32];   // 32 KB
    __shared__ float rsum[64], rsq[64], mu_s[64], rs_s[64];
    const int tid = threadIdx.x;
    const int lane = tid & 63;
    const int w = tid >> 6;        // 0..7  (n-wave)
    const int m0 = blockIdx.x * 64;
    const int q = lane >> 4;       // k-octet / D-row-quad
    const int r = lane & 15;
    const int wn = w * 64;

    floatx4 acc[4][4] = {};

    for (int k0 = 0; k0 < DIM; k0 += 32) {
        #pragma unroll
        for (int l = 0; l < 5; ++l) {
            int id = (l * 8 + w) * 64 + lane;      // wave-contiguous chunk ids
            if (id < 2304) {                        // wave-uniform branch
                if (id < 256) {                     // wave-uniform (A ids = waves 0..3 @ l=0)
                    int c = id >> 6, row = id & 63;
                    int gm = m0 + row; if (gm >= M) gm = M - 1;
                    load_lds16(&A[(size_t)gm * DIM + k0 + c * 8], &Asb[id * 8]);
                } else {
                    int b = id - 256;
                    int c = b >> 9, n = b & 511;
                    load_lds16(&B[(size_t)n * DIM + k0 + c * 8], &Bsb[b * 8]);
                }
            }
        }
        __syncthreads();
        shortx8 af[4], bf[4];
        #pragma unroll
        for (int mi = 0; mi < 4; ++mi)
            af[mi] = *(const shortx8*)&Asb[(q * 64 + mi * 16 + r) * 8];
        #pragma unroll
        for (int nj = 0; nj < 4; ++nj)
            bf[nj] = *(const shortx8*)&Bsb[(q * 512 + wn + nj * 16 + r) * 8];
        #pragma unroll
        for (int mi = 0; mi < 4; ++mi)
            #pragma unroll
            for (int nj = 0; nj < 4; ++nj)
                acc[mi][nj] = __builtin_amdgcn_mfma_f32_16x16x32_bf16(
                    af[mi], bf[nj], acc[mi][nj], 0, 0, 0);
        __syncthreads();
    }

    // ---- epilogue: ReLU + row stats + LayerNorm ----
    if (tid < 64) { rsum[tid] = 0.0f; rsq[tid] = 0.0f; }
    __syncthreads();

    float ps[4][4], pq[4][4];   // [mi][rg] partial sum / sumsq over this wave's 64 cols
    #pragma unroll
    for (int mi = 0; mi < 4; ++mi)
        #pragma unroll
        for (int rg = 0; rg < 4; ++rg) {
            float s = 0.0f, sq = 0.0f;
            #pragma unroll
            for (int nj = 0; nj < 4; ++nj) {
                float v = fmaxf(acc[mi][nj][rg], 0.0f);
                s += v; sq += v * v;
            }
            ps[mi][rg] = s; pq[mi][rg] = sq;
        }
    #pragma unroll
    for (int off = 1; off < 16; off <<= 1) {
        #pragma unroll
        for (int mi = 0; mi < 4; ++mi)
            #pragma unroll
            for (int rg = 0; rg < 4; ++rg) {
                ps[mi][rg] += __shfl_xor(ps[mi][rg], off);
                pq[mi][rg] += __shfl_xor(pq[mi][rg], off);
            }
    }
    if (r == 0) {
        #pragma unroll
        for (int mi = 0; mi < 4; ++mi)
            #pragma unroll
            for (int rg = 0; rg < 4; ++rg) {
                int row = mi * 16 + q * 4 + rg;
                atomicAdd(&rsum[row], ps[mi][rg]);
                atomicAdd(&rsq[row], pq[mi][rg]);
            }
    }
    __syncthreads();
    if (tid < 64) {
        float mu = rsum[tid] * (1.0f / DIM);
        float var = rsq[tid] * (1.0f / DIM) - mu * mu;
        mu_s[tid] = mu;
        rs_s[tid] = rsqrtf(var + 1e-5f);
    }
    __syncthreads();

    float g[4], bt[4];
    #pragma unroll
    for (int nj = 0; nj < 4; ++nj) {
        int col = wn + nj * 16 + r;
        g[nj] = gamma[col];
        bt[nj] = beta[col];
    }
    #pragma unroll
    for (int mi = 0; mi < 4; ++mi) {
        #pragma unroll
        for (int rg = 0; rg < 4; ++rg) {
            int row = mi * 16 + q * 4 + rg;
            int gm = m0 + row;
            if (gm < M) {
                float mu = mu_s[row], rstd = rs_s[row];
                #pragma unroll
                for (int nj = 0; nj < 4; ++nj) {
                    float v = fmaxf(acc[mi][nj][rg], 0.0f);
                    C[(size_t)gm * DIM + wn + nj * 16 + r] =
                        (v - mu) * rstd * g[nj] + bt[nj];
                }
            }
        }
    }
}

extern "C" void kernel_launch(void* const* d_in, const int* in_sizes, int n_in,
                              void* d_out, int out_size, void* d_ws, size_t ws_size,
                              hipStream_t stream) {
    const float* x     = (const float*)d_in[0];
    const float* W0    = (const float*)d_in[1];
    const float* W1    = (const float*)d_in[2];
    const float* W2    = (const float*)d_in[3];
    const float* gamma = (const float*)d_in[4];
    const float* beta  = (const float*)d_in[5];
    const int* s0  = (const int*)d_in[6];
    const int* dd0 = (const int*)d_in[7];
    const int* s1  = (const int*)d_in[8];
    const int* dd1 = (const int*)d_in[9];
    const int* s2  = (const int*)d_in[10];
    const int* dd2 = (const int*)d_in[11];
    float* out = (float*)d_out;

    // workspace layout (16B-aligned pieces)
    char* ws = (char*)d_ws;
    size_t off = 0;
    int* cnt = (int*)(ws + off);             off += 3u * N_NODES * 4u;          // 1.2 MB
    int* row_start = (int*)(ws + off);       off += (size_t)N_NODES * 4u;
    int* cursor = (int*)(ws + off);          off += (size_t)N_NODES * 4u;
    int* bsum = (int*)(ws + off);            off += 2048;
    int* boff = (int*)(ws + off);            off += 2048;
    int* src_tag = (int*)(ws + off);         off += (size_t)3 * NE * 4u;        // 2.4 MB
    unsigned short* Wc = (unsigned short*)(ws + off); off += (size_t)DIM * DIM * 2u;
    off = (off + 255) & ~255ull;
    unsigned short* xb = (unsigned short*)(ws + off); off += (size_t)N_NODES * DIM * 2u;  // 102.4 MB
    off = (off + 255) & ~255ull;
    unsigned short* xagg = (unsigned short*)(ws + off);                                   // 102.4 MB

    hipMemsetAsync(cnt, 0, (size_t)3 * N_NODES * sizeof(int), stream);

    combine_w_kernel<<<(DIM * DIM) / 256, 256, 0, stream>>>(W0, W1, W2, Wc);
    convert_x_kernel<<<(N_NODES * DIM / 8) / 256, 256, 0, stream>>>(x, xb);
    count_kernel<<<(3 * NE + 255) / 256, 256, 0, stream>>>(dd0, dd1, dd2, cnt);
    scan1_kernel<<<NBLK, 256, 0, stream>>>(cnt, bsum);
    scan2_kernel<<<1, 512, 0, stream>>>(bsum, boff);
    scan3_kernel<<<NBLK, 256, 0, stream>>>(cnt, boff, row_start, cursor);
    bin_kernel<<<(3 * NE + 255) / 256, 256, 0, stream>>>(
        s0, dd0, s1, dd1, s2, dd2, cursor, src_tag);
    gather_kernel<<<(N_NODES + 3) / 4, 256, 0, stream>>>(
        xb, row_start, cnt, src_tag, xagg);

    gemm_ln_kernel<<<(N_NODES + 63) / 64, 512, 0, stream>>>(
        xagg, Wc, gamma, beta, out, N_NODES);
}